// Round 19
// baseline (1030.122 us; speedup 1.0000x reference)
//
#include <hip/hip_runtime.h>
#include <hip/hip_bf16.h>

// ---------------------------------------------------------------------------
// Hetero-GNN forward: 6 SAGEConv (mean aggr, L2-norm) + 3 GCNConv + 3 BN.
// Round 19: R18 + write-amplification fix in batched bin_edges. The 256
// blocks/relation gave ~20B runs per (block,bin) -> 64B lines split across
// XCDs -> 7x write amp (497MB for 72MB payload). 64 blocks/relation gives
// ~80B runs (1.3 lines), per-block write set 125KB (L2-resident) -> lines
// written once. Everything else identical to R18.
// ---------------------------------------------------------------------------

#define GRID   2048
#define BLK    256
#define DSTR   64     // dsts per bin
#define BCAP   1536   // bin capacity (mean 1280, +7 sigma)
#define P1GB   64     // phase-1 blocks per relation (batched: long runs)
#define P1GF   256    // phase-1 blocks (fallback sequential path)
#define P1B    1024   // phase-1 threads
#define MAXBIN 2048   // max NBINS supported by bin_edges LDS
#define WSLOT  4096   // ushorts per weight slot (8 frags x 64 lanes x 8)
#define REP    8      // weight-table replicas

typedef __attribute__((ext_vector_type(8))) short bf16x8;          // MFMA A/B
typedef __attribute__((ext_vector_type(4))) float f32x4;           // MFMA C/D
typedef __attribute__((ext_vector_type(8))) unsigned short u16x8;  // bf16 row oct

__device__ inline short f2bf(float f) {
  __hip_bfloat16 h = __float2bfloat16(f);
  return *reinterpret_cast<short*>(&h);
}

__device__ inline float bf2f(unsigned short u) {
  union { unsigned int i; float f; } x;
  x.i = ((unsigned int)u) << 16;
  return x.f;
}

__device__ inline bf16x8 load_bf8(const float* p) {
  const float4 a = *(const float4*)p;
  const float4 b = *(const float4*)(p + 4);
  bf16x8 r;
  r[0] = f2bf(a.x); r[1] = f2bf(a.y); r[2] = f2bf(a.z); r[3] = f2bf(a.w);
  r[4] = f2bf(b.x); r[5] = f2bf(b.y); r[6] = f2bf(b.z); r[7] = f2bf(b.w);
  return r;
}

// ---- weight fragment packing (REP copies) ---------------------------------
struct WD { const float* w[15]; int k[15]; };

__global__ __launch_bounds__(256) void pack_wfrags(WD wd, unsigned short* tbl) {
  const int mi = blockIdx.y;
  const float* __restrict__ W = wd.w[mi];
  const int K = wd.k[mi];
  const int nf = (K >> 5) * 4;
  const int idx = blockIdx.x * 256 + threadIdx.x;
  if (idx >= nf * 64) return;
  const int frag = idx >> 6, lane = idx & 63;
  const int ks = frag >> 2, tt = frag & 3;
  const int kbase = ks * 32 + (lane >> 4) * 8;
  const int col = tt * 16 + (lane & 15);
  u16x8 r;
#pragma unroll
  for (int j = 0; j < 8; ++j)
    r[j] = (unsigned short)f2bf(W[(kbase + j) * 64 + col]);
#pragma unroll
  for (int rep = 0; rep < REP; ++rep)
    *(u16x8*)(tbl + ((size_t)rep * 15 + mi) * WSLOT + (size_t)idx * 8) = r;
}

// ---- f32 -> bf16 table conversion -----------------------------------------
__global__ __launch_bounds__(256) void cvt_bf16(
    const float* __restrict__ in, unsigned short* __restrict__ out, int n8) {
  for (int i = blockIdx.x * 256 + threadIdx.x; i < n8; i += gridDim.x * 256) {
    const float4 a = *(const float4*)(in + (size_t)i * 8);
    const float4 b = *(const float4*)(in + (size_t)i * 8 + 4);
    u16x8 r;
    r[0] = (unsigned short)f2bf(a.x); r[1] = (unsigned short)f2bf(a.y);
    r[2] = (unsigned short)f2bf(a.z); r[3] = (unsigned short)f2bf(a.w);
    r[4] = (unsigned short)f2bf(b.x); r[5] = (unsigned short)f2bf(b.y);
    r[6] = (unsigned short)f2bf(b.z); r[7] = (unsigned short)f2bf(b.w);
    *(u16x8*)(out + (size_t)i * 8) = r;
  }
}

// ---- phase 1: bin edges (batched over blockIdx.y relations) ---------------
struct EB { const int* ei[9]; int* cur[9]; int* buf[9]; };

__global__ __launch_bounds__(P1B) void bin_edges_b(EB eb, int E, int nbins) {
  const int rel = blockIdx.y;
  const int* __restrict__ ei = eb.ei[rel];
  int* __restrict__ bincur = eb.cur[rel];
  int* __restrict__ binbuf = eb.buf[rel];
  __shared__ int cnt[MAXBIN];
  __shared__ int cur[MAXBIN];
  const int t = threadIdx.x;
  for (int i = t; i < nbins; i += P1B) cnt[i] = 0;
  __syncthreads();
  const int per = (E + gridDim.x - 1) / gridDim.x;
  const int e0 = blockIdx.x * per;
  const int e1 = min(e0 + per, E);
  for (int e = e0 + t; e < e1; e += P1B)
    atomicAdd(&cnt[ei[E + e] / DSTR], 1);
  __syncthreads();
  for (int i = t; i < nbins; i += P1B) {
    const int c = cnt[i];
    cur[i] = c ? atomicAdd(&bincur[i], c) : 0;
  }
  __syncthreads();
  for (int e = e0 + t; e < e1; e += P1B) {
    const int d = ei[E + e];
    const int s = ei[e];
    const int b = d / DSTR;
    const int pos = atomicAdd(&cur[b], 1);
    if (pos < BCAP) binbuf[(size_t)b * BCAP + pos] = s | ((d - b * DSTR) << 17);
  }
}

// ---- GCN prepass: deg + dcoef; block 0 also zeroes BN stats ---------------
__global__ __launch_bounds__(256) void deg_from_bins(
    const int* __restrict__ bincur, const int* __restrict__ binbuf,
    int* __restrict__ deg, float* __restrict__ dcoef,
    float* __restrict__ stats, int N) {
  __shared__ int sdeg[DSTR];
  const int bin = blockIdx.x;
  const int t = threadIdx.x;
  if (bin == 0 && t < 128) stats[t] = 0.0f;
  if (t < DSTR) sdeg[t] = 0;
  __syncthreads();
  const int m = min(bincur[bin], BCAP);
  const int* bb = binbuf + (size_t)bin * BCAP;
  for (int j = t; j < m; j += 256) atomicAdd(&sdeg[bb[j] >> 17], 1);
  __syncthreads();
  const int d0 = bin * DSTR;
  if (t < DSTR && d0 + t < N) {
    deg[d0 + t] = sdeg[t];
    dcoef[d0 + t] = rsqrtf((float)sdeg[t] + 1.0f);
  }
}

// ---- phase 2: counting-sort by dl in LDS, then group-per-dst gather -------
template <int GCN>
__global__ __launch_bounds__(512) void bin_sort_agg(
    const unsigned short* __restrict__ x16, const int* __restrict__ bincur,
    const int* __restrict__ binbuf, const float* __restrict__ dcoef,
    float* __restrict__ agg, int* __restrict__ degout, int N) {
  __shared__ int scnt[DSTR];
  __shared__ int soff[DSTR];
  __shared__ int scur[DSTR];
  __shared__ int sorted[BCAP];
  const int t = threadIdx.x;
  const int bin = blockIdx.x;
  const int d0 = bin * DSTR;
  if (t < DSTR) scnt[t] = 0;
  __syncthreads();
  const int m = min(bincur[bin], BCAP);
  const int* bb = binbuf + (size_t)bin * BCAP;
  for (int j = t; j < m; j += 512) atomicAdd(&scnt[bb[j] >> 17], 1);
  __syncthreads();
  if (t < 64) {
    const int v = scnt[t];
    int incl = v;
#pragma unroll
    for (int o = 1; o < 64; o <<= 1) {
      const int u = __shfl_up(incl, o, 64);
      if (t >= o) incl += u;
    }
    soff[t] = incl - v;
    scur[t] = incl - v;
    if (!GCN && d0 + t < N) degout[d0 + t] = v;
  }
  __syncthreads();
  for (int j = t; j < m; j += 512) {
    const int wd = bb[j];
    const int pos = atomicAdd(&scur[wd >> 17], 1);
    sorted[pos] = wd & 0x1FFFF;
  }
  __syncthreads();
  const int grp = t >> 3;
  const int c8  = t & 7;
  if (d0 + grp < N) {
    const int beg = soff[grp];
    const int cnt = scnt[grp];
    float acc[8] = {0.f, 0.f, 0.f, 0.f, 0.f, 0.f, 0.f, 0.f};
    int i = 0;
    for (; i + 4 <= cnt; i += 4) {
      const int s0 = sorted[beg + i + 0];
      const int s1 = sorted[beg + i + 1];
      const int s2 = sorted[beg + i + 2];
      const int s3 = sorted[beg + i + 3];
      const u16x8 v0 = *(const u16x8*)(x16 + (size_t)s0 * 64 + c8 * 8);
      const u16x8 v1 = *(const u16x8*)(x16 + (size_t)s1 * 64 + c8 * 8);
      const u16x8 v2 = *(const u16x8*)(x16 + (size_t)s2 * 64 + c8 * 8);
      const u16x8 v3 = *(const u16x8*)(x16 + (size_t)s3 * 64 + c8 * 8);
      float c0 = 1.f, c1 = 1.f, c2 = 1.f, c3 = 1.f;
      if (GCN) { c0 = dcoef[s0]; c1 = dcoef[s1]; c2 = dcoef[s2]; c3 = dcoef[s3]; }
#pragma unroll
      for (int j = 0; j < 8; ++j)
        acc[j] += bf2f((unsigned short)v0[j]) * c0 + bf2f((unsigned short)v1[j]) * c1 +
                  bf2f((unsigned short)v2[j]) * c2 + bf2f((unsigned short)v3[j]) * c3;
    }
    for (; i < cnt; ++i) {
      const int s0 = sorted[beg + i];
      const u16x8 v0 = *(const u16x8*)(x16 + (size_t)s0 * 64 + c8 * 8);
      const float c0 = GCN ? dcoef[s0] : 1.0f;
#pragma unroll
      for (int j = 0; j < 8; ++j) acc[j] += bf2f((unsigned short)v0[j]) * c0;
    }
    float* ap = agg + (size_t)(d0 + grp) * 64 + c8 * 8;
    float4 o0, o1;
    o0.x = acc[0]; o0.y = acc[1]; o0.z = acc[2]; o0.w = acc[3];
    o1.x = acc[4]; o1.y = acc[5]; o1.z = acc[6]; o1.w = acc[7];
    *(float4*)ap = o0;
    *(float4*)(ap + 4) = o1;
  }
}

// ---- MFMA epilogues (R16 form: grid 1024, fragment-table prologue) --------
template <int CD>
__global__ __launch_bounds__(256) void sage_ep(
    const float* __restrict__ agg, const int* __restrict__ deg,
    const float* __restrict__ xdst, const unsigned short* __restrict__ wtab,
    int slotWl, int slotWr, const float* __restrict__ bias,
    float* __restrict__ out, unsigned short* __restrict__ out16, int n) {
  const int lane = threadIdx.x & 63;
  const int lr   = lane & 15;
  const int kg   = lane >> 4;
  const int wid  = (blockIdx.x * 256 + threadIdx.x) >> 6;
  const int nw   = (gridDim.x * 256) >> 6;
  const unsigned short* base =
      wtab + (size_t)(blockIdx.x & (REP - 1)) * 15 * WSLOT;
  const unsigned short* tWl = base + (size_t)slotWl * WSLOT;
  const unsigned short* tWr = base + (size_t)slotWr * WSLOT;
  bf16x8 wl[2][4], wr[CD / 32][4];
#pragma unroll
  for (int f = 0; f < 8; ++f)
    wl[f >> 2][f & 3] = *(const bf16x8*)(tWl + ((size_t)f * 64 + lane) * 8);
#pragma unroll
  for (int f = 0; f < (CD / 32) * 4; ++f)
    wr[f >> 2][f & 3] = *(const bf16x8*)(tWr + ((size_t)f * 64 + lane) * 8);
  const int ntiles = (n + 15) >> 4;
  for (int tile = wid; tile < ntiles; tile += nw) {
    const int r0 = tile << 4;
    const int ra = min(r0 + lr, n - 1);
    const float inva = 1.0f / fmaxf((float)deg[ra], 1.0f);
    f32x4 acc[4];
#pragma unroll
    for (int t = 0; t < 4; ++t) { acc[t][0]=0.f; acc[t][1]=0.f; acc[t][2]=0.f; acc[t][3]=0.f; }
#pragma unroll
    for (int ks = 0; ks < 2; ++ks) {
      const float* ap = agg + (size_t)ra * 64 + ks * 32 + kg * 8;
      const float4 a0 = *(const float4*)ap;
      const float4 a1 = *(const float4*)(ap + 4);
      bf16x8 af;
      af[0] = f2bf(a0.x * inva); af[1] = f2bf(a0.y * inva);
      af[2] = f2bf(a0.z * inva); af[3] = f2bf(a0.w * inva);
      af[4] = f2bf(a1.x * inva); af[5] = f2bf(a1.y * inva);
      af[6] = f2bf(a1.z * inva); af[7] = f2bf(a1.w * inva);
#pragma unroll
      for (int t = 0; t < 4; ++t)
        acc[t] = __builtin_amdgcn_mfma_f32_16x16x32_bf16(af, wl[ks][t], acc[t], 0, 0, 0);
    }
#pragma unroll
    for (int ks = 0; ks < CD / 32; ++ks) {
      const bf16x8 xf = load_bf8(xdst + (size_t)ra * CD + ks * 32 + kg * 8);
#pragma unroll
      for (int t = 0; t < 4; ++t)
        acc[t] = __builtin_amdgcn_mfma_f32_16x16x32_bf16(xf, wr[ks][t], acc[t], 0, 0, 0);
    }
#pragma unroll
    for (int t = 0; t < 4; ++t) {
      const float bv = bias[t * 16 + lr];
#pragma unroll
      for (int i = 0; i < 4; ++i) acc[t][i] += bv;
    }
    float ssi[4];
#pragma unroll
    for (int i = 0; i < 4; ++i) {
      float s = acc[0][i] * acc[0][i] + acc[1][i] * acc[1][i] +
                acc[2][i] * acc[2][i] + acc[3][i] * acc[3][i];
      s += __shfl_xor(s, 1, 64); s += __shfl_xor(s, 2, 64);
      s += __shfl_xor(s, 4, 64); s += __shfl_xor(s, 8, 64);
      ssi[i] = fmaxf(sqrtf(s), 1e-12f);
    }
#pragma unroll
    for (int t = 0; t < 4; ++t)
#pragma unroll
      for (int i = 0; i < 4; ++i) {
        const int r = r0 + kg * 4 + i;
        if (r < n) {
          const float val = fmaxf(acc[t][i] / ssi[i], 0.0f);
          out[(size_t)r * 64 + t * 16 + lr] = val;
          if (out16) out16[(size_t)r * 64 + t * 16 + lr] = (unsigned short)f2bf(val);
        }
      }
  }
}

__global__ __launch_bounds__(256) void gcn_ep(
    const float* __restrict__ agg, const float* __restrict__ x,
    const int* __restrict__ deg, const unsigned short* __restrict__ wtab,
    int slotW, const float* __restrict__ bias, float* __restrict__ v,
    float* __restrict__ stats, int n) {
  __shared__ float ssum[64], ssq[64];
  if (threadIdx.x < 64) { ssum[threadIdx.x] = 0.f; ssq[threadIdx.x] = 0.f; }
  __syncthreads();
  const int lane = threadIdx.x & 63;
  const int lr   = lane & 15;
  const int kg   = lane >> 4;
  const int wid  = (blockIdx.x * 256 + threadIdx.x) >> 6;
  const int nw   = (gridDim.x * 256) >> 6;
  const unsigned short* tW =
      wtab + ((size_t)(blockIdx.x & (REP - 1)) * 15 + slotW) * WSLOT;
  bf16x8 wf[2][4];
#pragma unroll
  for (int f = 0; f < 8; ++f)
    wf[f >> 2][f & 3] = *(const bf16x8*)(tW + ((size_t)f * 64 + lane) * 8);
  float psum[4] = {0.f, 0.f, 0.f, 0.f}, psq[4] = {0.f, 0.f, 0.f, 0.f};
  const int ntiles = (n + 15) >> 4;
  for (int tile = wid; tile < ntiles; tile += nw) {
    const int r0 = tile << 4;
    const int ra = min(r0 + lr, n - 1);
    const float dd = (float)deg[ra] + 1.0f;
    const float ca = rsqrtf(dd);
    const float cb = 1.0f / dd;
    f32x4 acc[4];
#pragma unroll
    for (int t = 0; t < 4; ++t) { acc[t][0]=0.f; acc[t][1]=0.f; acc[t][2]=0.f; acc[t][3]=0.f; }
#pragma unroll
    for (int ks = 0; ks < 2; ++ks) {
      const float* ap = agg + (size_t)ra * 64 + ks * 32 + kg * 8;
      const float* xp = x   + (size_t)ra * 64 + ks * 32 + kg * 8;
      const float4 a0 = *(const float4*)ap;
      const float4 a1 = *(const float4*)(ap + 4);
      const float4 x0 = *(const float4*)xp;
      const float4 x1 = *(const float4*)(xp + 4);
      bf16x8 af;
      af[0] = f2bf(a0.x * ca + x0.x * cb); af[1] = f2bf(a0.y * ca + x0.y * cb);
      af[2] = f2bf(a0.z * ca + x0.z * cb); af[3] = f2bf(a0.w * ca + x0.w * cb);
      af[4] = f2bf(a1.x * ca + x1.x * cb); af[5] = f2bf(a1.y * ca + x1.y * cb);
      af[6] = f2bf(a1.z * ca + x1.z * cb); af[7] = f2bf(a1.w * ca + x1.w * cb);
#pragma unroll
      for (int t = 0; t < 4; ++t)
        acc[t] = __builtin_amdgcn_mfma_f32_16x16x32_bf16(af, wf[ks][t], acc[t], 0, 0, 0);
    }
#pragma unroll
    for (int t = 0; t < 4; ++t) {
      const float bv = bias[t * 16 + lr];
#pragma unroll
      for (int i = 0; i < 4; ++i) {
        const int r = r0 + kg * 4 + i;
        if (r < n) {
          const float val = fmaxf(acc[t][i] + bv, 0.0f);
          v[(size_t)r * 64 + t * 16 + lr] = val;
          psum[t] += val;
          psq[t]  += val * val;
        }
      }
    }
  }
#pragma unroll
  for (int t = 0; t < 4; ++t) {
    atomicAdd(&ssum[t * 16 + lr], psum[t]);
    atomicAdd(&ssq[t * 16 + lr], psq[t]);
  }
  __syncthreads();
  if (threadIdx.x < 64) {
    atomicAdd(&stats[threadIdx.x], ssum[threadIdx.x]);
    atomicAdd(&stats[64 + threadIdx.x], ssq[threadIdx.x]);
  }
}

// out = (v - mean) * rsqrt(var + 1e-5) * gam + bet; optional bf16 copy
__global__ __launch_bounds__(BLK) void bn_apply(
    const float* __restrict__ v, const float* __restrict__ stats,
    const float* __restrict__ gam, const float* __restrict__ bet,
    float* __restrict__ out, unsigned short* __restrict__ out16, int n) {
  __shared__ float sm[64], sr[64], sg[64], sbt[64];
  if (threadIdx.x < 64) {
    const float m   = stats[threadIdx.x] / (float)n;
    const float var = stats[64 + threadIdx.x] / (float)n - m * m;
    sm[threadIdx.x]  = m;
    sr[threadIdx.x]  = rsqrtf(var + 1e-5f);
    sg[threadIdx.x]  = gam[threadIdx.x];
    sbt[threadIdx.x] = bet[threadIdx.x];
  }
  __syncthreads();
  const int lane = threadIdx.x & 63;
  const int w    = threadIdx.x >> 6;
  for (int r = blockIdx.x * 4 + w; r < n; r += gridDim.x * 4) {
    const float val =
        (v[(size_t)r * 64 + lane] - sm[lane]) * sr[lane] * sg[lane] + sbt[lane];
    out[(size_t)r * 64 + lane] = val;
    if (out16) out16[(size_t)r * 64 + lane] = (unsigned short)f2bf(val);
  }
}

extern "C" void kernel_launch(void* const* d_in, const int* in_sizes, int n_in,
                              void* d_out, int out_size, void* d_ws, size_t ws_size,
                              hipStream_t stream) {
  const float* game_x  = (const float*)d_in[0];
  const float* state_x = (const float*)d_in[1];
  const float* pc_x    = (const float*)d_in[2];
  const int* ei_vv  = (const int*)d_in[3];
  const int* ei_hvs = (const int*)d_in[4];
  const int* ei_hsv = (const int*)d_in[5];
  const int* ei_ivs = (const int*)d_in[6];
  const int* ei_isv = (const int*)d_in[7];
  const int* ei_ss  = (const int*)d_in[8];
  const int* ei_pp  = (const int*)d_in[9];
  const int* ei_ps  = (const int*)d_in[10];
  const int* ei_sp  = (const int*)d_in[11];
  const float* s_Wl[6], *s_b[6], *s_Wr[6];
  for (int i = 0; i < 6; ++i) {
    s_Wl[i] = (const float*)d_in[12 + 3 * i];
    s_b[i]  = (const float*)d_in[13 + 3 * i];
    s_Wr[i] = (const float*)d_in[14 + 3 * i];
  }
  const float* gcfg_W = (const float*)d_in[30];
  const float* gcfg_b = (const float*)d_in[31];
  const float* gpc_W  = (const float*)d_in[32];
  const float* gpc_b  = (const float*)d_in[33];
  const float* gst_W  = (const float*)d_in[34];
  const float* gst_b  = (const float*)d_in[35];
  const float* bncfg_g = (const float*)d_in[36];
  const float* bncfg_b = (const float*)d_in[37];
  const float* bnpc_g  = (const float*)d_in[38];
  const float* bnpc_b  = (const float*)d_in[39];
  const float* bnst_g  = (const float*)d_in[40];
  const float* bnst_b  = (const float*)d_in[41];

  const int N = in_sizes[1] / 64;   // nodes per type (100000)
  const int E = in_sizes[3] / 2;    // edges per relation (2000000)
  const int NBINS = (N + DSTR - 1) / DSTR;  // 1563

  const size_t nb = (size_t)N * 64;
  // fixed workspace prefix (~92 MB)
  float* A    = (float*)d_ws;                 // nb f32
  float* X    = A + nb;                       // nb f32
  unsigned short* S16  = (unsigned short*)(X + nb);
  unsigned short* T16a = S16 + nb;
  unsigned short* T16b = T16a + nb;
  int*   DEG    = (int*)(T16b + nb);          // N
  float* DCOEF  = (float*)(DEG + N);          // N
  float* STAT   = (float*)(DCOEF + N);        // 128
  unsigned short* WTAB = (unsigned short*)(STAT + 128);  // REP*15*WSLOT
  int*   BINCUR = (int*)(WTAB + (size_t)REP * 15 * WSLOT);  // 9*NBINS
  int*   BINBUF0 = BINCUR + 9 * (size_t)NBINS;              // nbuf*NBINS*BCAP

  // runtime decision: 9 binbufs (batched build) if ws fits, else 1 (R16 path)
  const size_t fixed_bytes = (size_t)((char*)BINBUF0 - (char*)d_ws);
  const size_t per_buf = (size_t)NBINS * BCAP * sizeof(int);
  const int nbuf = (fixed_bytes + 9 * per_buf <= ws_size) ? 9 : 1;

  float* out_s = (float*)d_out;
  float* out_g = out_s + nb;
  float* out_p = out_g + nb;

  // relation order of use
  const int* eis[9] = {ei_hsv, ei_isv, ei_vv, ei_sp, ei_pp,
                       ei_hvs, ei_ivs, ei_ps, ei_ss};
  int* curp[9];
  int* bufp[9];
  for (int r = 0; r < 9; ++r) {
    curp[r] = BINCUR + (size_t)r * NBINS;
    bufp[r] = BINBUF0 + (size_t)(r % nbuf) * ((size_t)NBINS * BCAP);
  }

  // pack weight fragment tables
  WD wd;
  const int cds[6] = {32, 64, 32, 64, 64, 64};
  for (int i = 0; i < 6; ++i) { wd.w[i] = s_Wl[i]; wd.k[i] = 64; }
  for (int i = 0; i < 6; ++i) { wd.w[6 + i] = s_Wr[i]; wd.k[6 + i] = cds[i]; }
  wd.w[12] = gcfg_W; wd.k[12] = 64;
  wd.w[13] = gpc_W;  wd.k[13] = 64;
  wd.w[14] = gst_W;  wd.k[14] = 64;
  pack_wfrags<<<dim3(2, 15), 256, 0, stream>>>(wd, WTAB);

  // zero ALL relation cursors once
  hipMemsetAsync(BINCUR, 0, 9 * (size_t)NBINS * sizeof(int), stream);

  // state_x bf16 copy
  cvt_bf16<<<2048, 256, 0, stream>>>(state_x, S16, (int)(nb / 8));

  if (nbuf == 9) {   // batched: build all 9 binnings in ONE dispatch
    EB eb;
    for (int r = 0; r < 9; ++r) { eb.ei[r] = eis[r]; eb.cur[r] = curp[r]; eb.buf[r] = bufp[r]; }
    bin_edges_b<<<dim3(P1GB, 9), P1B, 0, stream>>>(eb, E, NBINS);
  }

  auto build_bins = [&](int rel) {
    if (nbuf == 9) return;   // already built
    EB eb;
    eb.ei[0] = eis[rel]; eb.cur[0] = curp[rel]; eb.buf[0] = bufp[rel];
    bin_edges_b<<<dim3(P1GF, 1), P1B, 0, stream>>>(eb, E, NBINS);
  };

  auto run_sage = [&](int rel, const unsigned short* src16, const float* xdst,
                      int cd, int wi, float* outbuf, unsigned short* out16) {
    build_bins(rel);
    bin_sort_agg<0><<<NBINS, 512, 0, stream>>>(src16, curp[rel], bufp[rel],
                                               DCOEF, A, DEG, N);
    if (cd == 32)
      sage_ep<32><<<1024, 256, 0, stream>>>(A, DEG, xdst, WTAB, wi, 6 + wi,
                                            s_b[wi], outbuf, out16, N);
    else
      sage_ep<64><<<1024, 256, 0, stream>>>(A, DEG, xdst, WTAB, wi, 6 + wi,
                                            s_b[wi], outbuf, out16, N);
  };

  auto run_gcn_bn = [&](int rel, const unsigned short* src16, const float* x,
                        int wslot, const float* b, const float* bng,
                        const float* bnb, float* vbuf, float* outbuf,
                        unsigned short* out16) {
    build_bins(rel);
    deg_from_bins<<<NBINS, 256, 0, stream>>>(curp[rel], bufp[rel], DEG, DCOEF,
                                             STAT, N);
    bin_sort_agg<1><<<NBINS, 512, 0, stream>>>(src16, curp[rel], bufp[rel],
                                               DCOEF, A, DEG, N);
    gcn_ep<<<1024, 256, 0, stream>>>(A, x, DEG, WTAB, wslot, b, vbuf, STAT, N);
    bn_apply<<<GRID, BLK, 0, stream>>>(vbuf, STAT, bng, bnb, outbuf, out16, N);
  };

  // ---- graph ----
  // g1 = relu(sage1(state->game))                        -> X
  run_sage(0, S16, game_x, 32, 0, X, nullptr);
  // g2 = relu(sage2(state->g1))                          -> out_g + T16a
  run_sage(1, S16, X, 64, 1, out_g, T16a);
  // g  = bn(relu(gcn(g2, v_v)))   v->X                   -> out_g + T16a
  run_gcn_bn(2, T16a, out_g, 12, gcfg_b, bncfg_g, bncfg_b, X, out_g, T16a);
  // p1 = relu(sage3(state->pc))                          -> X + T16b
  run_sage(3, S16, pc_x, 32, 2, X, T16b);
  // p  = bn(relu(gcn(p1, pc_pc))) v->out_p (inplace BN)  -> out_p + T16b
  run_gcn_bn(4, T16b, X, 13, gpc_b, bnpc_g, bnpc_b, out_p, out_p, T16b);
  // s1 = relu(sage4(g->state))                           -> X
  run_sage(5, T16a, state_x, 64, 3, X, nullptr);
  // s2 = relu(sage5(g->s1))                              -> out_s
  run_sage(6, T16a, X, 64, 4, out_s, nullptr);
  // s3 = relu(sage6(p->s2))                              -> X + T16a
  run_sage(7, T16b, out_s, 64, 5, X, T16a);
  // s  = bn(relu(gcn(s3, s_s)))   v->out_s (inplace BN)  -> out_s
  run_gcn_bn(8, T16a, X, 14, gst_b, bnst_g, bnst_b, out_s, out_s, nullptr);
}

// Round 20
// 809.298 us; speedup vs baseline: 1.2729x; 1.2729x over previous
//
#include <hip/hip_runtime.h>
#include <hip/hip_bf16.h>

// ---------------------------------------------------------------------------
// Hetero-GNN forward: 6 SAGEConv (mean aggr, L2-norm) + 3 GCNConv + 3 BN.
// Round 20: two-level binning replaces the one-shot scatter (R18: 300us,
// 497MB write amp from ~1563 open lines/block; R19 showed run length is not
// the lever).
//  - coarse_bin: 1024-dst bins (98) -> 98 open lines/block, amp ~1.2.
//  - refine_bins: one block per (rel, coarse bin) EXCLUSIVELY owns its 16
//    fine bins -> zero cross-block interleave; writes fine bincur directly.
// Coarse buffer aliased over A/X/S16/T16a (dead until after binning).
// Phase 2 + epilogues identical to R18 (926us best).
// ---------------------------------------------------------------------------

#define GRID   2048
#define BLK    256
#define DSTR   64     // fine dsts per bin
#define BCAP   1536   // fine bin capacity
#define CCAP   21504  // coarse bin capacity (mean 20408, +7.7 sigma)
#define P1B    1024
#define WSLOT  4096   // ushorts per weight slot
#define REP    8      // weight-table replicas

typedef __attribute__((ext_vector_type(8))) short bf16x8;          // MFMA A/B
typedef __attribute__((ext_vector_type(4))) float f32x4;           // MFMA C/D
typedef __attribute__((ext_vector_type(8))) unsigned short u16x8;  // bf16 row oct

__device__ inline short f2bf(float f) {
  __hip_bfloat16 h = __float2bfloat16(f);
  return *reinterpret_cast<short*>(&h);
}

__device__ inline float bf2f(unsigned short u) {
  union { unsigned int i; float f; } x;
  x.i = ((unsigned int)u) << 16;
  return x.f;
}

__device__ inline bf16x8 load_bf8(const float* p) {
  const float4 a = *(const float4*)p;
  const float4 b = *(const float4*)(p + 4);
  bf16x8 r;
  r[0] = f2bf(a.x); r[1] = f2bf(a.y); r[2] = f2bf(a.z); r[3] = f2bf(a.w);
  r[4] = f2bf(b.x); r[5] = f2bf(b.y); r[6] = f2bf(b.z); r[7] = f2bf(b.w);
  return r;
}

// ---- weight fragment packing (REP copies) ---------------------------------
struct WD { const float* w[15]; int k[15]; };

__global__ __launch_bounds__(256) void pack_wfrags(WD wd, unsigned short* tbl) {
  const int mi = blockIdx.y;
  const float* __restrict__ W = wd.w[mi];
  const int K = wd.k[mi];
  const int nf = (K >> 5) * 4;
  const int idx = blockIdx.x * 256 + threadIdx.x;
  if (idx >= nf * 64) return;
  const int frag = idx >> 6, lane = idx & 63;
  const int ks = frag >> 2, tt = frag & 3;
  const int kbase = ks * 32 + (lane >> 4) * 8;
  const int col = tt * 16 + (lane & 15);
  u16x8 r;
#pragma unroll
  for (int j = 0; j < 8; ++j)
    r[j] = (unsigned short)f2bf(W[(kbase + j) * 64 + col]);
#pragma unroll
  for (int rep = 0; rep < REP; ++rep)
    *(u16x8*)(tbl + ((size_t)rep * 15 + mi) * WSLOT + (size_t)idx * 8) = r;
}

// ---- f32 -> bf16 table conversion -----------------------------------------
__global__ __launch_bounds__(256) void cvt_bf16(
    const float* __restrict__ in, unsigned short* __restrict__ out, int n8) {
  for (int i = blockIdx.x * 256 + threadIdx.x; i < n8; i += gridDim.x * 256) {
    const float4 a = *(const float4*)(in + (size_t)i * 8);
    const float4 b = *(const float4*)(in + (size_t)i * 8 + 4);
    u16x8 r;
    r[0] = (unsigned short)f2bf(a.x); r[1] = (unsigned short)f2bf(a.y);
    r[2] = (unsigned short)f2bf(a.z); r[3] = (unsigned short)f2bf(a.w);
    r[4] = (unsigned short)f2bf(b.x); r[5] = (unsigned short)f2bf(b.y);
    r[6] = (unsigned short)f2bf(b.z); r[7] = (unsigned short)f2bf(b.w);
    *(u16x8*)(out + (size_t)i * 8) = r;
  }
}

// ---- phase 1a: coarse binning (1024-dst bins), word = src | ((d&1023)<<17)
struct P9e { const int* p[9]; };

__global__ __launch_bounds__(P1B) void coarse_bin(
    P9e eis, int rel0, int* __restrict__ ccur, int* __restrict__ cbuf,
    int E, int nc) {
  const int ry = blockIdx.y;
  const int* __restrict__ ei = eis.p[rel0 + ry];
  int* __restrict__ cc = ccur + (size_t)ry * nc;
  int* __restrict__ cb = cbuf + (size_t)ry * nc * CCAP;
  __shared__ int cnt[128];
  __shared__ int cur[128];
  const int t = threadIdx.x;
  if (t < nc) cnt[t] = 0;
  __syncthreads();
  const int per = (E + gridDim.x - 1) / gridDim.x;
  const int e0 = blockIdx.x * per;
  const int e1 = min(e0 + per, E);
  for (int e = e0 + t; e < e1; e += P1B)
    atomicAdd(&cnt[ei[E + e] >> 10], 1);
  __syncthreads();
  if (t < nc) {
    const int c = cnt[t];
    cur[t] = c ? atomicAdd(&cc[t], c) : 0;
  }
  __syncthreads();
  for (int e = e0 + t; e < e1; e += P1B) {
    const int d = ei[E + e];
    const int s = ei[e];
    const int b = d >> 10;
    const int pos = atomicAdd(&cur[b], 1);
    if (pos < CCAP) cb[(size_t)b * CCAP + pos] = s | ((d & 1023) << 17);
  }
}

// ---- phase 1b: refine — one block owns one coarse bin's 16 fine bins ------
__global__ __launch_bounds__(P1B) void refine_bins(
    const int* __restrict__ ccur, const int* __restrict__ cbuf,
    int* __restrict__ fcur, int* __restrict__ fbuf, int nc, int nbins) {
  const int ry = blockIdx.y;
  const int c  = blockIdx.x;
  const int m = min(ccur[(size_t)ry * nc + c], CCAP);
  const int* __restrict__ src = cbuf + ((size_t)ry * nc + c) * CCAP;
  int* __restrict__ fc = fcur + (size_t)ry * nbins;
  int* __restrict__ fb = fbuf + (size_t)ry * nbins * BCAP;
  __shared__ int fcnt[16];
  const int t = threadIdx.x;
  if (t < 16) fcnt[t] = 0;
  __syncthreads();
  for (int i = t; i < m; i += P1B) {
    const int w = src[i];
    const int dlc = w >> 17;          // 0..1023 within coarse bin
    const int f = dlc >> 6;           // fine bin 0..15
    const int pos = atomicAdd(&fcnt[f], 1);
    if (pos < BCAP) {
      const int fbin = c * 16 + f;
      fb[(size_t)fbin * BCAP + pos] = (w & 0x1FFFF) | ((dlc & 63) << 17);
    }
  }
  __syncthreads();
  if (t < 16) {
    const int fbin = c * 16 + t;
    if (fbin < nbins) fc[fbin] = min(fcnt[t], BCAP);
  }
}

// ---- GCN prepass: deg + dcoef; block 0 also zeroes BN stats ---------------
__global__ __launch_bounds__(256) void deg_from_bins(
    const int* __restrict__ bincur, const int* __restrict__ binbuf,
    int* __restrict__ deg, float* __restrict__ dcoef,
    float* __restrict__ stats, int N) {
  __shared__ int sdeg[DSTR];
  const int bin = blockIdx.x;
  const int t = threadIdx.x;
  if (bin == 0 && t < 128) stats[t] = 0.0f;
  if (t < DSTR) sdeg[t] = 0;
  __syncthreads();
  const int m = min(bincur[bin], BCAP);
  const int* bb = binbuf + (size_t)bin * BCAP;
  for (int j = t; j < m; j += 256) atomicAdd(&sdeg[bb[j] >> 17], 1);
  __syncthreads();
  const int d0 = bin * DSTR;
  if (t < DSTR && d0 + t < N) {
    deg[d0 + t] = sdeg[t];
    dcoef[d0 + t] = rsqrtf((float)sdeg[t] + 1.0f);
  }
}

// ---- phase 2: counting-sort by dl in LDS, then group-per-dst gather -------
template <int GCN>
__global__ __launch_bounds__(512) void bin_sort_agg(
    const unsigned short* __restrict__ x16, const int* __restrict__ bincur,
    const int* __restrict__ binbuf, const float* __restrict__ dcoef,
    float* __restrict__ agg, int* __restrict__ degout, int N) {
  __shared__ int scnt[DSTR];
  __shared__ int soff[DSTR];
  __shared__ int scur[DSTR];
  __shared__ int sorted[BCAP];
  const int t = threadIdx.x;
  const int bin = blockIdx.x;
  const int d0 = bin * DSTR;
  if (t < DSTR) scnt[t] = 0;
  __syncthreads();
  const int m = min(bincur[bin], BCAP);
  const int* bb = binbuf + (size_t)bin * BCAP;
  for (int j = t; j < m; j += 512) atomicAdd(&scnt[bb[j] >> 17], 1);
  __syncthreads();
  if (t < 64) {
    const int v = scnt[t];
    int incl = v;
#pragma unroll
    for (int o = 1; o < 64; o <<= 1) {
      const int u = __shfl_up(incl, o, 64);
      if (t >= o) incl += u;
    }
    soff[t] = incl - v;
    scur[t] = incl - v;
    if (!GCN && d0 + t < N) degout[d0 + t] = v;
  }
  __syncthreads();
  for (int j = t; j < m; j += 512) {
    const int wd = bb[j];
    const int pos = atomicAdd(&scur[wd >> 17], 1);
    sorted[pos] = wd & 0x1FFFF;
  }
  __syncthreads();
  const int grp = t >> 3;
  const int c8  = t & 7;
  if (d0 + grp < N) {
    const int beg = soff[grp];
    const int cnt = scnt[grp];
    float acc[8] = {0.f, 0.f, 0.f, 0.f, 0.f, 0.f, 0.f, 0.f};
    int i = 0;
    for (; i + 4 <= cnt; i += 4) {
      const int s0 = sorted[beg + i + 0];
      const int s1 = sorted[beg + i + 1];
      const int s2 = sorted[beg + i + 2];
      const int s3 = sorted[beg + i + 3];
      const u16x8 v0 = *(const u16x8*)(x16 + (size_t)s0 * 64 + c8 * 8);
      const u16x8 v1 = *(const u16x8*)(x16 + (size_t)s1 * 64 + c8 * 8);
      const u16x8 v2 = *(const u16x8*)(x16 + (size_t)s2 * 64 + c8 * 8);
      const u16x8 v3 = *(const u16x8*)(x16 + (size_t)s3 * 64 + c8 * 8);
      float c0 = 1.f, c1 = 1.f, c2 = 1.f, c3 = 1.f;
      if (GCN) { c0 = dcoef[s0]; c1 = dcoef[s1]; c2 = dcoef[s2]; c3 = dcoef[s3]; }
#pragma unroll
      for (int j = 0; j < 8; ++j)
        acc[j] += bf2f((unsigned short)v0[j]) * c0 + bf2f((unsigned short)v1[j]) * c1 +
                  bf2f((unsigned short)v2[j]) * c2 + bf2f((unsigned short)v3[j]) * c3;
    }
    for (; i < cnt; ++i) {
      const int s0 = sorted[beg + i];
      const u16x8 v0 = *(const u16x8*)(x16 + (size_t)s0 * 64 + c8 * 8);
      const float c0 = GCN ? dcoef[s0] : 1.0f;
#pragma unroll
      for (int j = 0; j < 8; ++j) acc[j] += bf2f((unsigned short)v0[j]) * c0;
    }
    float* ap = agg + (size_t)(d0 + grp) * 64 + c8 * 8;
    float4 o0, o1;
    o0.x = acc[0]; o0.y = acc[1]; o0.z = acc[2]; o0.w = acc[3];
    o1.x = acc[4]; o1.y = acc[5]; o1.z = acc[6]; o1.w = acc[7];
    *(float4*)ap = o0;
    *(float4*)(ap + 4) = o1;
  }
}

// ---- MFMA epilogues (R16/R18 form) ----------------------------------------
template <int CD>
__global__ __launch_bounds__(256) void sage_ep(
    const float* __restrict__ agg, const int* __restrict__ deg,
    const float* __restrict__ xdst, const unsigned short* __restrict__ wtab,
    int slotWl, int slotWr, const float* __restrict__ bias,
    float* __restrict__ out, unsigned short* __restrict__ out16, int n) {
  const int lane = threadIdx.x & 63;
  const int lr   = lane & 15;
  const int kg   = lane >> 4;
  const int wid  = (blockIdx.x * 256 + threadIdx.x) >> 6;
  const int nw   = (gridDim.x * 256) >> 6;
  const unsigned short* base =
      wtab + (size_t)(blockIdx.x & (REP - 1)) * 15 * WSLOT;
  const unsigned short* tWl = base + (size_t)slotWl * WSLOT;
  const unsigned short* tWr = base + (size_t)slotWr * WSLOT;
  bf16x8 wl[2][4], wr[CD / 32][4];
#pragma unroll
  for (int f = 0; f < 8; ++f)
    wl[f >> 2][f & 3] = *(const bf16x8*)(tWl + ((size_t)f * 64 + lane) * 8);
#pragma unroll
  for (int f = 0; f < (CD / 32) * 4; ++f)
    wr[f >> 2][f & 3] = *(const bf16x8*)(tWr + ((size_t)f * 64 + lane) * 8);
  const int ntiles = (n + 15) >> 4;
  for (int tile = wid; tile < ntiles; tile += nw) {
    const int r0 = tile << 4;
    const int ra = min(r0 + lr, n - 1);
    const float inva = 1.0f / fmaxf((float)deg[ra], 1.0f);
    f32x4 acc[4];
#pragma unroll
    for (int t = 0; t < 4; ++t) { acc[t][0]=0.f; acc[t][1]=0.f; acc[t][2]=0.f; acc[t][3]=0.f; }
#pragma unroll
    for (int ks = 0; ks < 2; ++ks) {
      const float* ap = agg + (size_t)ra * 64 + ks * 32 + kg * 8;
      const float4 a0 = *(const float4*)ap;
      const float4 a1 = *(const float4*)(ap + 4);
      bf16x8 af;
      af[0] = f2bf(a0.x * inva); af[1] = f2bf(a0.y * inva);
      af[2] = f2bf(a0.z * inva); af[3] = f2bf(a0.w * inva);
      af[4] = f2bf(a1.x * inva); af[5] = f2bf(a1.y * inva);
      af[6] = f2bf(a1.z * inva); af[7] = f2bf(a1.w * inva);
#pragma unroll
      for (int t = 0; t < 4; ++t)
        acc[t] = __builtin_amdgcn_mfma_f32_16x16x32_bf16(af, wl[ks][t], acc[t], 0, 0, 0);
    }
#pragma unroll
    for (int ks = 0; ks < CD / 32; ++ks) {
      const bf16x8 xf = load_bf8(xdst + (size_t)ra * CD + ks * 32 + kg * 8);
#pragma unroll
      for (int t = 0; t < 4; ++t)
        acc[t] = __builtin_amdgcn_mfma_f32_16x16x32_bf16(xf, wr[ks][t], acc[t], 0, 0, 0);
    }
#pragma unroll
    for (int t = 0; t < 4; ++t) {
      const float bv = bias[t * 16 + lr];
#pragma unroll
      for (int i = 0; i < 4; ++i) acc[t][i] += bv;
    }
    float ssi[4];
#pragma unroll
    for (int i = 0; i < 4; ++i) {
      float s = acc[0][i] * acc[0][i] + acc[1][i] * acc[1][i] +
                acc[2][i] * acc[2][i] + acc[3][i] * acc[3][i];
      s += __shfl_xor(s, 1, 64); s += __shfl_xor(s, 2, 64);
      s += __shfl_xor(s, 4, 64); s += __shfl_xor(s, 8, 64);
      ssi[i] = fmaxf(sqrtf(s), 1e-12f);
    }
#pragma unroll
    for (int t = 0; t < 4; ++t)
#pragma unroll
      for (int i = 0; i < 4; ++i) {
        const int r = r0 + kg * 4 + i;
        if (r < n) {
          const float val = fmaxf(acc[t][i] / ssi[i], 0.0f);
          out[(size_t)r * 64 + t * 16 + lr] = val;
          if (out16) out16[(size_t)r * 64 + t * 16 + lr] = (unsigned short)f2bf(val);
        }
      }
  }
}

__global__ __launch_bounds__(256) void gcn_ep(
    const float* __restrict__ agg, const float* __restrict__ x,
    const int* __restrict__ deg, const unsigned short* __restrict__ wtab,
    int slotW, const float* __restrict__ bias, float* __restrict__ v,
    float* __restrict__ stats, int n) {
  __shared__ float ssum[64], ssq[64];
  if (threadIdx.x < 64) { ssum[threadIdx.x] = 0.f; ssq[threadIdx.x] = 0.f; }
  __syncthreads();
  const int lane = threadIdx.x & 63;
  const int lr   = lane & 15;
  const int kg   = lane >> 4;
  const int wid  = (blockIdx.x * 256 + threadIdx.x) >> 6;
  const int nw   = (gridDim.x * 256) >> 6;
  const unsigned short* tW =
      wtab + ((size_t)(blockIdx.x & (REP - 1)) * 15 + slotW) * WSLOT;
  bf16x8 wf[2][4];
#pragma unroll
  for (int f = 0; f < 8; ++f)
    wf[f >> 2][f & 3] = *(const bf16x8*)(tW + ((size_t)f * 64 + lane) * 8);
  float psum[4] = {0.f, 0.f, 0.f, 0.f}, psq[4] = {0.f, 0.f, 0.f, 0.f};
  const int ntiles = (n + 15) >> 4;
  for (int tile = wid; tile < ntiles; tile += nw) {
    const int r0 = tile << 4;
    const int ra = min(r0 + lr, n - 1);
    const float dd = (float)deg[ra] + 1.0f;
    const float ca = rsqrtf(dd);
    const float cb = 1.0f / dd;
    f32x4 acc[4];
#pragma unroll
    for (int t = 0; t < 4; ++t) { acc[t][0]=0.f; acc[t][1]=0.f; acc[t][2]=0.f; acc[t][3]=0.f; }
#pragma unroll
    for (int ks = 0; ks < 2; ++ks) {
      const float* ap = agg + (size_t)ra * 64 + ks * 32 + kg * 8;
      const float* xp = x   + (size_t)ra * 64 + ks * 32 + kg * 8;
      const float4 a0 = *(const float4*)ap;
      const float4 a1 = *(const float4*)(ap + 4);
      const float4 x0 = *(const float4*)xp;
      const float4 x1 = *(const float4*)(xp + 4);
      bf16x8 af;
      af[0] = f2bf(a0.x * ca + x0.x * cb); af[1] = f2bf(a0.y * ca + x0.y * cb);
      af[2] = f2bf(a0.z * ca + x0.z * cb); af[3] = f2bf(a0.w * ca + x0.w * cb);
      af[4] = f2bf(a1.x * ca + x1.x * cb); af[5] = f2bf(a1.y * ca + x1.y * cb);
      af[6] = f2bf(a1.z * ca + x1.z * cb); af[7] = f2bf(a1.w * ca + x1.w * cb);
#pragma unroll
      for (int t = 0; t < 4; ++t)
        acc[t] = __builtin_amdgcn_mfma_f32_16x16x32_bf16(af, wf[ks][t], acc[t], 0, 0, 0);
    }
#pragma unroll
    for (int t = 0; t < 4; ++t) {
      const float bv = bias[t * 16 + lr];
#pragma unroll
      for (int i = 0; i < 4; ++i) {
        const int r = r0 + kg * 4 + i;
        if (r < n) {
          const float val = fmaxf(acc[t][i] + bv, 0.0f);
          v[(size_t)r * 64 + t * 16 + lr] = val;
          psum[t] += val;
          psq[t]  += val * val;
        }
      }
    }
  }
#pragma unroll
  for (int t = 0; t < 4; ++t) {
    atomicAdd(&ssum[t * 16 + lr], psum[t]);
    atomicAdd(&ssq[t * 16 + lr], psq[t]);
  }
  __syncthreads();
  if (threadIdx.x < 64) {
    atomicAdd(&stats[threadIdx.x], ssum[threadIdx.x]);
    atomicAdd(&stats[64 + threadIdx.x], ssq[threadIdx.x]);
  }
}

// out = (v - mean) * rsqrt(var + 1e-5) * gam + bet; optional bf16 copy
__global__ __launch_bounds__(BLK) void bn_apply(
    const float* __restrict__ v, const float* __restrict__ stats,
    const float* __restrict__ gam, const float* __restrict__ bet,
    float* __restrict__ out, unsigned short* __restrict__ out16, int n) {
  __shared__ float sm[64], sr[64], sg[64], sbt[64];
  if (threadIdx.x < 64) {
    const float m   = stats[threadIdx.x] / (float)n;
    const float var = stats[64 + threadIdx.x] / (float)n - m * m;
    sm[threadIdx.x]  = m;
    sr[threadIdx.x]  = rsqrtf(var + 1e-5f);
    sg[threadIdx.x]  = gam[threadIdx.x];
    sbt[threadIdx.x] = bet[threadIdx.x];
  }
  __syncthreads();
  const int lane = threadIdx.x & 63;
  const int w    = threadIdx.x >> 6;
  for (int r = blockIdx.x * 4 + w; r < n; r += gridDim.x * 4) {
    const float val =
        (v[(size_t)r * 64 + lane] - sm[lane]) * sr[lane] * sg[lane] + sbt[lane];
    out[(size_t)r * 64 + lane] = val;
    if (out16) out16[(size_t)r * 64 + lane] = (unsigned short)f2bf(val);
  }
}

extern "C" void kernel_launch(void* const* d_in, const int* in_sizes, int n_in,
                              void* d_out, int out_size, void* d_ws, size_t ws_size,
                              hipStream_t stream) {
  const float* game_x  = (const float*)d_in[0];
  const float* state_x = (const float*)d_in[1];
  const float* pc_x    = (const float*)d_in[2];
  const int* ei_vv  = (const int*)d_in[3];
  const int* ei_hvs = (const int*)d_in[4];
  const int* ei_hsv = (const int*)d_in[5];
  const int* ei_ivs = (const int*)d_in[6];
  const int* ei_isv = (const int*)d_in[7];
  const int* ei_ss  = (const int*)d_in[8];
  const int* ei_pp  = (const int*)d_in[9];
  const int* ei_ps  = (const int*)d_in[10];
  const int* ei_sp  = (const int*)d_in[11];
  const float* s_Wl[6], *s_b[6], *s_Wr[6];
  for (int i = 0; i < 6; ++i) {
    s_Wl[i] = (const float*)d_in[12 + 3 * i];
    s_b[i]  = (const float*)d_in[13 + 3 * i];
    s_Wr[i] = (const float*)d_in[14 + 3 * i];
  }
  const float* gcfg_W = (const float*)d_in[30];
  const float* gcfg_b = (const float*)d_in[31];
  const float* gpc_W  = (const float*)d_in[32];
  const float* gpc_b  = (const float*)d_in[33];
  const float* gst_W  = (const float*)d_in[34];
  const float* gst_b  = (const float*)d_in[35];
  const float* bncfg_g = (const float*)d_in[36];
  const float* bncfg_b = (const float*)d_in[37];
  const float* bnpc_g  = (const float*)d_in[38];
  const float* bnpc_b  = (const float*)d_in[39];
  const float* bnst_g  = (const float*)d_in[40];
  const float* bnst_b  = (const float*)d_in[41];

  const int N = in_sizes[1] / 64;   // nodes per type (100000)
  const int E = in_sizes[3] / 2;    // edges per relation (2000000)
  const int NBINS = (N + DSTR - 1) / DSTR;   // 1563
  const int NC = (N + 1023) >> 10;           // 98 coarse bins

  const size_t nb = (size_t)N * 64;
  // fixed workspace prefix
  float* A    = (float*)d_ws;                 // nb f32
  float* X    = A + nb;                       // nb f32
  unsigned short* S16  = (unsigned short*)(X + nb);
  unsigned short* T16a = S16 + nb;
  unsigned short* T16b = T16a + nb;
  int*   DEG    = (int*)(T16b + nb);          // N
  float* DCOEF  = (float*)(DEG + N);          // N
  float* STAT   = (float*)(DCOEF + N);        // 128
  unsigned short* WTAB = (unsigned short*)(STAT + 128);  // REP*15*WSLOT
  int*   CCUR   = (int*)(WTAB + (size_t)REP * 15 * WSLOT);  // 9*NC
  int*   BINCUR = CCUR + 9 * (size_t)NC;                    // 9*NBINS
  int*   BINBUF0 = BINCUR + 9 * (size_t)NBINS;              // nbuf*NBINS*BCAP
  // coarse buffer aliases A..T16a region (dead until after binning)
  int*   CBUF   = (int*)d_ws;

  const size_t fixed_bytes = (size_t)((char*)BINBUF0 - (char*)d_ws);
  const size_t per_buf = (size_t)NBINS * BCAP * sizeof(int);
  const int nbuf = (fixed_bytes + 9 * per_buf <= ws_size) ? 9 : 1;

  float* out_s = (float*)d_out;
  float* out_g = out_s + nb;
  float* out_p = out_g + nb;

  // relation order of use
  P9e eis = {{ei_hsv, ei_isv, ei_vv, ei_sp, ei_pp, ei_hvs, ei_ivs, ei_ps, ei_ss}};
  int* curp[9];
  int* bufp[9];
  for (int r = 0; r < 9; ++r) {
    curp[r] = BINCUR + (size_t)r * NBINS;
    bufp[r] = BINBUF0 + (size_t)(r % nbuf) * ((size_t)NBINS * BCAP);
  }

  // pack weight fragment tables (WTAB is outside the coarse alias region)
  WD wd;
  const int cds[6] = {32, 64, 32, 64, 64, 64};
  for (int i = 0; i < 6; ++i) { wd.w[i] = s_Wl[i]; wd.k[i] = 64; }
  for (int i = 0; i < 6; ++i) { wd.w[6 + i] = s_Wr[i]; wd.k[6 + i] = cds[i]; }
  wd.w[12] = gcfg_W; wd.k[12] = 64;
  wd.w[13] = gpc_W;  wd.k[13] = 64;
  wd.w[14] = gst_W;  wd.k[14] = 64;
  pack_wfrags<<<dim3(2, 15), 256, 0, stream>>>(wd, WTAB);

  if (nbuf == 9) {
    // batched: coarse-bin all 9 relations, refine, then free the alias region
    hipMemsetAsync(CCUR, 0, 9 * (size_t)NC * sizeof(int), stream);
    coarse_bin<<<dim3(256, 9), P1B, 0, stream>>>(eis, 0, CCUR, CBUF, E, NC);
    refine_bins<<<dim3(NC, 9), P1B, 0, stream>>>(CCUR, CBUF, BINCUR, BINBUF0,
                                                 NC, NBINS);
  }
  // state_x bf16 copy (AFTER binning: S16 overlaps the coarse alias region)
  cvt_bf16<<<2048, 256, 0, stream>>>(state_x, S16, (int)(nb / 8));

  auto build_bins = [&](int rel) {
    if (nbuf == 9) return;  // already built
    // sequential fallback: coarse (aliases A only: NC*CCAP*4 ~ 8.4MB) + refine
    hipMemsetAsync(CCUR, 0, (size_t)NC * sizeof(int), stream);
    coarse_bin<<<dim3(256, 1), P1B, 0, stream>>>(eis, rel, CCUR, CBUF, E, NC);
    refine_bins<<<dim3(NC, 1), P1B, 0, stream>>>(CCUR, CBUF, curp[rel],
                                                 bufp[rel], NC, NBINS);
  };

  auto run_sage = [&](int rel, const unsigned short* src16, const float* xdst,
                      int cd, int wi, float* outbuf, unsigned short* out16) {
    build_bins(rel);
    bin_sort_agg<0><<<NBINS, 512, 0, stream>>>(src16, curp[rel], bufp[rel],
                                               DCOEF, A, DEG, N);
    if (cd == 32)
      sage_ep<32><<<1024, 256, 0, stream>>>(A, DEG, xdst, WTAB, wi, 6 + wi,
                                            s_b[wi], outbuf, out16, N);
    else
      sage_ep<64><<<1024, 256, 0, stream>>>(A, DEG, xdst, WTAB, wi, 6 + wi,
                                            s_b[wi], outbuf, out16, N);
  };

  auto run_gcn_bn = [&](int rel, const unsigned short* src16, const float* x,
                        int wslot, const float* b, const float* bng,
                        const float* bnb, float* vbuf, float* outbuf,
                        unsigned short* out16) {
    build_bins(rel);
    deg_from_bins<<<NBINS, 256, 0, stream>>>(curp[rel], bufp[rel], DEG, DCOEF,
                                             STAT, N);
    bin_sort_agg<1><<<NBINS, 512, 0, stream>>>(src16, curp[rel], bufp[rel],
                                               DCOEF, A, DEG, N);
    gcn_ep<<<1024, 256, 0, stream>>>(A, x, DEG, WTAB, wslot, b, vbuf, STAT, N);
    bn_apply<<<GRID, BLK, 0, stream>>>(vbuf, STAT, bng, bnb, outbuf, out16, N);
  };

  // ---- graph ----
  // g1 = relu(sage1(state->game))                        -> X
  run_sage(0, S16, game_x, 32, 0, X, nullptr);
  // g2 = relu(sage2(state->g1))                          -> out_g + T16a
  run_sage(1, S16, X, 64, 1, out_g, T16a);
  // g  = bn(relu(gcn(g2, v_v)))   v->X                   -> out_g + T16a
  run_gcn_bn(2, T16a, out_g, 12, gcfg_b, bncfg_g, bncfg_b, X, out_g, T16a);
  // p1 = relu(sage3(state->pc))                          -> X + T16b
  run_sage(3, S16, pc_x, 32, 2, X, T16b);
  // p  = bn(relu(gcn(p1, pc_pc))) v->out_p (inplace BN)  -> out_p + T16b
  run_gcn_bn(4, T16b, X, 13, gpc_b, bnpc_g, bnpc_b, out_p, out_p, T16b);
  // s1 = relu(sage4(g->state))                           -> X
  run_sage(5, T16a, state_x, 64, 3, X, nullptr);
  // s2 = relu(sage5(g->s1))                              -> out_s
  run_sage(6, T16a, X, 64, 4, out_s, nullptr);
  // s3 = relu(sage6(p->s2))                              -> X + T16a
  run_sage(7, T16b, out_s, 64, 5, X, T16a);
  // s  = bn(relu(gcn(s3, s_s)))   v->out_s (inplace BN)  -> out_s
  run_gcn_bn(8, T16a, X, 14, gst_b, bnst_g, bnst_b, out_s, out_s, nullptr);
}